// Round 5
// baseline (509.601 us; speedup 1.0000x reference)
//
#include <hip/hip_runtime.h>
#include <hip/hip_bf16.h>

// GCN 2-layer forward, CSR-gather formulation (no float atomics).
// R5 changes:
//  - hist8/fill8 edge-stream loads are NON-TEMPORAL (nt): R4 showed the 25.6MB
//    streaming reads per team evicted the partially-filled csr_src lines from
//    the XCD's 4MB L2 before they merged (WRITE 174MB for a 12.8MB array).
//  - cursor is initialized to rowptr (k_copy), so fill needs one atomicAdd and
//    no random rowptr read per edge.

#define NTEAM 8

__global__ void k_hist8(const int* __restrict__ dst, int* __restrict__ cnt,
                        int E, int n) {
    int team = blockIdx.x & (NTEAM - 1);
    int sub  = blockIdx.x >> 3;
    int nsub = gridDim.x >> 3;
    int nb   = (n + NTEAM - 1) / NTEAM;
    int lo = team * nb;
    int hi = min(n, lo + nb);
    for (int e = sub * blockDim.x + threadIdx.x; e < E; e += nsub * blockDim.x) {
        int d = __builtin_nontemporal_load(dst + e);
        if (d >= lo && d < hi) atomicAdd(&cnt[d], 1);
    }
}

__global__ void k_fill8(const int* __restrict__ src, const int* __restrict__ dst,
                        int* __restrict__ cursor, int* __restrict__ csr_src,
                        int E, int n) {
    int team = blockIdx.x & (NTEAM - 1);
    int sub  = blockIdx.x >> 3;
    int nsub = gridDim.x >> 3;
    int nb   = (n + NTEAM - 1) / NTEAM;
    int lo = team * nb;
    int hi = min(n, lo + nb);
    for (int e = sub * blockDim.x + threadIdx.x; e < E; e += nsub * blockDim.x) {
        int d = __builtin_nontemporal_load(dst + e);
        if (d >= lo && d < hi) {
            int s = __builtin_nontemporal_load(src + e);
            int p = atomicAdd(&cursor[d], 1);
            csr_src[p] = s;
        }
    }
}

__global__ void k_copy(const int* __restrict__ a, int* __restrict__ b, int n) {
    int i = blockIdx.x * blockDim.x + threadIdx.x;
    if (i < n) b[i] = a[i];
}

__global__ void k_dinv(const int* __restrict__ cnt, float* __restrict__ dinv, int n) {
    int i = blockIdx.x * blockDim.x + threadIdx.x;
    if (i < n) dinv[i] = rsqrtf(1.0f + (float)cnt[i]);
}

// Per-block (1024 elems) sum of cnt -> bsum[b]
__global__ void k_scan_bsum(const int* __restrict__ cnt, int* __restrict__ bsum, int n) {
    __shared__ int lds[256];
    int base = blockIdx.x * 1024;
    int s = 0;
    for (int i = threadIdx.x; i < 1024; i += 256) {
        int g = base + i;
        if (g < n) s += cnt[g];
    }
    lds[threadIdx.x] = s;
    __syncthreads();
    for (int off = 128; off > 0; off >>= 1) {
        if (threadIdx.x < off) lds[threadIdx.x] += lds[threadIdx.x + off];
        __syncthreads();
    }
    if (threadIdx.x == 0) bsum[blockIdx.x] = lds[0];
}

// Exclusive scan of bsum (nb ~ 98, single thread is fine); also rowptr[n]=total.
__global__ void k_scan_off(int* __restrict__ bsum, int* __restrict__ rowptr, int nb, int n) {
    if (blockIdx.x == 0 && threadIdx.x == 0) {
        int run = 0;
        for (int i = 0; i < nb; i++) { int t = bsum[i]; bsum[i] = run; run += t; }
        rowptr[n] = run;
    }
}

// Final: exclusive scan within block + block offset -> rowptr[i]
__global__ void k_scan_final(const int* __restrict__ cnt, const int* __restrict__ bsum,
                             int* __restrict__ rowptr, int n) {
    __shared__ int lds[256];
    int base = blockIdx.x * 1024;
    int idx0 = base + threadIdx.x * 4;
    int v[4];
    #pragma unroll
    for (int i = 0; i < 4; i++) { int g = idx0 + i; v[i] = (g < n) ? cnt[g] : 0; }
    int t = v[0] + v[1] + v[2] + v[3];
    lds[threadIdx.x] = t;
    __syncthreads();
    for (int off = 1; off < 256; off <<= 1) {
        int val = lds[threadIdx.x];
        int add = (threadIdx.x >= off) ? lds[threadIdx.x - off] : 0;
        __syncthreads();
        lds[threadIdx.x] = val + add;
        __syncthreads();
    }
    int run = (threadIdx.x ? lds[threadIdx.x - 1] : 0) + bsum[blockIdx.x];
    #pragma unroll
    for (int i = 0; i < 4; i++) {
        int g = idx0 + i;
        if (g < n) rowptr[g] = run;
        run += v[i];
    }
}

// xw1 = x[n,128] @ W1[128,64]. Thread-per-row; acc[64] in VGPRs (all indices
// compile-time via full unroll); W1 addresses are lane-uniform -> scalar loads.
__global__ __launch_bounds__(256) void k_gemm1(const float* __restrict__ x,
                                               const float* __restrict__ W1,
                                               float* __restrict__ xw, int n) {
    int row = blockIdx.x * blockDim.x + threadIdx.x;
    if (row >= n) return;
    const float* xr = x + (size_t)row * 128;

    float acc[64];
    #pragma unroll
    for (int c = 0; c < 64; ++c) acc[c] = 0.f;

    for (int k4 = 0; k4 < 32; ++k4) {  // dynamic loop: small body, x read once
        float4 xv = *reinterpret_cast<const float4*>(xr + k4 * 4);
        const float* wp = W1 + (size_t)k4 * 4 * 64;  // rows k4*4 .. k4*4+3
        #pragma unroll
        for (int c = 0; c < 64; ++c) {
            acc[c] = fmaf(xv.x, wp[c], acc[c]);
            acc[c] = fmaf(xv.y, wp[64 + c], acc[c]);
            acc[c] = fmaf(xv.z, wp[128 + c], acc[c]);
            acc[c] = fmaf(xv.w, wp[192 + c], acc[c]);
        }
    }

    float* outp = xw + (size_t)row * 64;
    #pragma unroll
    for (int c = 0; c < 64; c += 4) {
        *reinterpret_cast<float4*>(outp + c) =
            make_float4(acc[c], acc[c + 1], acc[c + 2], acc[c + 3]);
    }
}

// Fused layer1 aggregate + tanh + GEMM2 (64->2 via wave reduction).
// One wave per dst node; lane = feature.
__global__ void k_agg1(const int* __restrict__ rowptr, const int* __restrict__ csr_src,
                       const float* __restrict__ dinv, const float* __restrict__ xw1,
                       const float* __restrict__ b1, const float* __restrict__ W2,
                       float* __restrict__ xw2, int n) {
    int lane = threadIdx.x & 63;
    float b1v = b1[lane];
    float w2a = W2[lane * 2 + 0];
    float w2b = W2[lane * 2 + 1];
    int wid = blockIdx.x * (blockDim.x >> 6) + (threadIdx.x >> 6);
    int wtot = gridDim.x * (blockDim.x >> 6);
    for (int d = wid; d < n; d += wtot) {
        int base = rowptr[d], end = rowptr[d + 1];
        float dd = dinv[d];
        float acc = xw1[(size_t)d * 64 + lane] * dd * dd;  // self loop
        int j = base;
        for (; j + 4 <= end; j += 4) {
            int s0 = csr_src[j + 0], s1 = csr_src[j + 1];
            int s2 = csr_src[j + 2], s3 = csr_src[j + 3];
            float n0 = dinv[s0] * dd, n1 = dinv[s1] * dd;
            float n2 = dinv[s2] * dd, n3 = dinv[s3] * dd;
            float v0 = xw1[(size_t)s0 * 64 + lane];
            float v1 = xw1[(size_t)s1 * 64 + lane];
            float v2 = xw1[(size_t)s2 * 64 + lane];
            float v3 = xw1[(size_t)s3 * 64 + lane];
            acc = fmaf(v0, n0, acc);
            acc = fmaf(v1, n1, acc);
            acc = fmaf(v2, n2, acc);
            acc = fmaf(v3, n3, acc);
        }
        for (; j < end; ++j) {
            int s = csr_src[j];
            acc = fmaf(xw1[(size_t)s * 64 + lane], dinv[s] * dd, acc);
        }
        float h = tanhf(acc + b1v);
        float p0 = h * w2a, p1 = h * w2b;
        #pragma unroll
        for (int m = 32; m >= 1; m >>= 1) {
            p0 += __shfl_xor(p0, m);
            p1 += __shfl_xor(p1, m);
        }
        if (lane == 0) *reinterpret_cast<float2*>(xw2 + (size_t)d * 2) = make_float2(p0, p1);
    }
}

// Fused layer2 aggregate + tanh + classifier. One wave per node:
// 32 edge-slots x 2 features in parallel, shfl tree reduce over slots.
__global__ void k_agg2(const int* __restrict__ rowptr, const int* __restrict__ csr_src,
                       const float* __restrict__ dinv, const float* __restrict__ xw2,
                       const float* __restrict__ b2, const float* __restrict__ Wc,
                       const float* __restrict__ bc,
                       float* __restrict__ out, float* __restrict__ hout, int n) {
    int lane = threadIdx.x & 63;
    int slot = lane >> 1;  // 0..31
    int f = lane & 1;      // feature 0/1
    float b2v = b2[f];
    int wid = blockIdx.x * (blockDim.x >> 6) + (threadIdx.x >> 6);
    int wtot = gridDim.x * (blockDim.x >> 6);
    for (int d = wid; d < n; d += wtot) {
        int base = rowptr[d], end = rowptr[d + 1];
        float dd = dinv[d];
        float acc = (slot == 0) ? xw2[(size_t)d * 2 + f] * dd * dd : 0.f;  // self loop once
        for (int j = base + slot; j < end; j += 32) {
            int s = csr_src[j];
            acc = fmaf(xw2[(size_t)s * 2 + f], dinv[s] * dd, acc);
        }
        #pragma unroll
        for (int m = 32; m >= 2; m >>= 1) acc += __shfl_xor(acc, m);
        float h = tanhf(acc + b2v);          // lane0: h(f=0), lane1: h(f=1), replicated
        float other = __shfl_xor(h, 1);
        if (lane == 0) {
            *reinterpret_cast<float2*>(hout + (size_t)d * 2) = make_float2(h, other);
            float4 o;
            o.x = fmaf(h, Wc[0], fmaf(other, Wc[4], bc[0]));
            o.y = fmaf(h, Wc[1], fmaf(other, Wc[5], bc[1]));
            o.z = fmaf(h, Wc[2], fmaf(other, Wc[6], bc[2]));
            o.w = fmaf(h, Wc[3], fmaf(other, Wc[7], bc[3]));
            *reinterpret_cast<float4*>(out + (size_t)d * 4) = o;
        }
    }
}

extern "C" void kernel_launch(void* const* d_in, const int* in_sizes, int n_in,
                              void* d_out, int out_size, void* d_ws, size_t ws_size,
                              hipStream_t stream) {
    const float* x  = (const float*)d_in[0];
    const int* ei   = (const int*)d_in[1];
    const float* W1 = (const float*)d_in[2];
    const float* b1 = (const float*)d_in[3];
    const float* W2 = (const float*)d_in[4];
    const float* b2 = (const float*)d_in[5];
    const float* Wc = (const float*)d_in[6];
    const float* bc = (const float*)d_in[7];

    const int N = in_sizes[0] / 128;
    const int E = in_sizes[1] / 2;
    const int* src = ei;
    const int* dst = ei + E;

    float* out  = (float*)d_out;        // [N,4]
    float* hout = out + (size_t)N * 4;  // [N,2]

    // Workspace layout (keep 16B alignment: big 16-divisible arrays first).
    char* ws = (char*)d_ws;
    int*   csr_src = (int*)ws;                           // E
    float* xw1     = (float*)(csr_src + E);              // 64N
    int*   cnt     = (int*)(xw1 + (size_t)N * 64);       // N (hist, then cursor)
    float* dinv    = (float*)(cnt + N);                  // N
    float* xw2     = dinv + N;                           // 2N
    int*   rowptr  = (int*)(xw2 + (size_t)N * 2);        // N+1
    int*   bsum    = rowptr + N + 1;                     // ~128

    const int NB = (N + 1023) / 1024;

    hipMemsetAsync(cnt, 0, (size_t)N * sizeof(int), stream);
    k_hist8<<<2048, 256, 0, stream>>>(dst, cnt, E, N);
    k_dinv<<<(N + 255) / 256, 256, 0, stream>>>(cnt, dinv, N);
    k_scan_bsum<<<NB, 256, 0, stream>>>(cnt, bsum, N);
    k_scan_off<<<1, 64, 0, stream>>>(bsum, rowptr, NB, N);
    k_scan_final<<<NB, 256, 0, stream>>>(cnt, bsum, rowptr, N);
    k_copy<<<(N + 255) / 256, 256, 0, stream>>>(rowptr, cnt, N);  // cursor = rowptr
    k_fill8<<<2048, 256, 0, stream>>>(src, dst, cnt, csr_src, E, N);

    k_gemm1<<<(N + 255) / 256, 256, 0, stream>>>(x, W1, xw1, N);
    k_agg1<<<2048, 256, 0, stream>>>(rowptr, csr_src, dinv, xw1, b1, W2, xw2, N);
    k_agg2<<<2048, 256, 0, stream>>>(rowptr, csr_src, dinv, xw2, b2, Wc, bc, out, hout, N);
}